// Round 1
// baseline (26791.919 us; speedup 1.0000x reference)
//
#include <hip/hip_runtime.h>
#include <cstddef>

// Problem constants (from reference setup_inputs)
#define S_ 512
#define B_ 64
#define I_ 256
#define H_ 1024

// ---------------------------------------------------------------------------
// Transpose: out[c*R + r] = in[r*C + c].  R,C multiples of 32.
// Used only for Wx (xproj needs WxT). Wh is consumed row-major directly.
// ---------------------------------------------------------------------------
__global__ __launch_bounds__(256) void transpose_k(const float* __restrict__ in,
                                                   float* __restrict__ out,
                                                   int R, int C) {
  __shared__ float t[32][33];
  int c0 = blockIdx.x * 32, r0 = blockIdx.y * 32;
  int x = threadIdx.x & 31, y = threadIdx.x >> 5;
  for (int i = 0; i < 32; i += 8) {
    t[y + i][x] = in[(size_t)(r0 + y + i) * C + (c0 + x)];
  }
  __syncthreads();
  for (int i = 0; i < 32; i += 8) {
    out[(size_t)(c0 + y + i) * R + (r0 + x)] = t[x][y + i];
  }
}

// ---------------------------------------------------------------------------
// xproj: out[m*H + j] = dot(x[m, 0:256], WxT[:, j]) + bx[j]   (unchanged)
// ---------------------------------------------------------------------------
__global__ __launch_bounds__(256) void xproj_kernel(const float* __restrict__ x,
                                                    const float* __restrict__ WxT,
                                                    const float* __restrict__ bx,
                                                    float* __restrict__ out) {
  __shared__ float xs[4][I_];
  int tid = threadIdx.x;
  int j = blockIdx.x * 256 + tid;
  size_t m0 = (size_t)blockIdx.y * 4;
  const float* xrow = x + m0 * I_;
  for (int r = 0; r < 4; ++r) xs[r][tid] = xrow[(size_t)r * I_ + tid];
  __syncthreads();

  float bj = bx[j];
  float a0 = bj, a1 = bj, a2 = bj, a3 = bj;
  const float* wp = WxT + j;
  for (int k = 0; k < I_; k += 4) {
    float w0 = wp[(size_t)(k + 0) * H_];
    float w1 = wp[(size_t)(k + 1) * H_];
    float w2 = wp[(size_t)(k + 2) * H_];
    float w3 = wp[(size_t)(k + 3) * H_];
    float4 v0 = *(const float4*)&xs[0][k];
    float4 v1 = *(const float4*)&xs[1][k];
    float4 v2 = *(const float4*)&xs[2][k];
    float4 v3 = *(const float4*)&xs[3][k];
    a0 += w0 * v0.x + w1 * v0.y + w2 * v0.z + w3 * v0.w;
    a1 += w0 * v1.x + w1 * v1.y + w2 * v1.z + w3 * v1.w;
    a2 += w0 * v2.x + w1 * v2.y + w2 * v2.z + w3 * v2.w;
    a3 += w0 * v3.x + w1 * v3.y + w2 * v3.z + w3 * v3.w;
  }
  out[(m0 + 0) * H_ + j] = a0;
  out[(m0 + 1) * H_ + j] = a1;
  out[(m0 + 2) * H_ + j] = a2;
  out[(m0 + 3) * H_ + j] = a3;
}

// ---------------------------------------------------------------------------
// Persistent cooperative recurrence kernel.
//   grid = 256 blocks x 256 threads, 1 block/CU (128 KB LDS).
//   Block (g = blk&3, jt = blk>>2): owns j columns [jt*16, +16) for batch
//   rows [g*16, +16).  Wh tile (16 rows x 1024) lives in LDS for ALL steps.
//   Batches are independent -> sync only among the 64 blocks of group g,
//   via a monotonic device-scope counter + threadfence (cross-XCD safe).
//   h state lives in d_out slot t (xproj_t before, h_t after), as before.
// ---------------------------------------------------------------------------
__global__ __launch_bounds__(256) void rnn_persistent(const float* __restrict__ Wh,
                                                      const float* __restrict__ bh,
                                                      float* __restrict__ out,
                                                      unsigned* __restrict__ bar) {
  // 64 KB each, 128 KB total. float4-XOR swizzle kills bank conflicts.
  __shared__ float4 Ws4[16][256];  // Ws4[jj][k4] = Wh[j0+jj][4k..4k+3] (swizzled)
  __shared__ float4 Hs4[16][256];  // Hs4[bb][k4] = h_prev[b0+bb][4k..] (swizzled)

  const int tid = threadIdx.x;
  const int g  = blockIdx.x & 3;   // batch-group
  const int jt = blockIdx.x >> 2;  // j-tile
  const int j0 = jt * 16, b0 = g * 16;

  // ---- preload Wh rows j0..j0+15 into LDS once (coalesced, row-major) ----
  {
    const int rj = tid >> 4, kq = tid & 15;
    const float4* wh4 = (const float4*)(Wh + (size_t)(j0 + rj) * H_);
    #pragma unroll
    for (int it = 0; it < 16; ++it) {
      int k4 = kq + (it << 4);
      Ws4[rj][k4 ^ (rj & 7)] = wh4[k4];
    }
  }

  const int jj = tid & 15, bb = tid >> 4;
  const int jsw = jj & 7, bsw = bb & 7;
  const float4* __restrict__ wrow = &Ws4[jj][0];
  const float4* __restrict__ hrow = &Hs4[bb][0];
  const float bh_j = bh[j0 + jj];
  const size_t oidx = (size_t)(b0 + bb) * H_ + (size_t)(j0 + jj);
  float* const out_last = out + (size_t)S_ * B_ * H_;

  __syncthreads();

  for (int t = 0; t < S_; ++t) {
    float s = 0.f;
    if (t > 0) {
      // ---- stage h_{t-1} rows b0..b0+15 into LDS (16 float4 per thread) ----
      const float4* hp4 =
          (const float4*)(out + (size_t)(t - 1) * B_ * H_ + (size_t)b0 * H_);
      const int sb = tid >> 4, sk = tid & 15;
      #pragma unroll
      for (int it = 0; it < 16; ++it) {
        int k4 = sk + (it << 4);
        Hs4[sb][k4 ^ (sb & 7)] = hp4[sb * 256 + k4];
      }
      __syncthreads();

      // ---- dot: 256 float4 pairs from LDS, 8 interleaved accumulators ----
      float acc[8] = {0.f, 0.f, 0.f, 0.f, 0.f, 0.f, 0.f, 0.f};
      for (int kb = 0; kb < 256; kb += 8) {
        #pragma unroll
        for (int u = 0; u < 8; ++u) {
          float4 w = wrow[(kb + u) ^ jsw];
          float4 h = hrow[(kb + u) ^ bsw];
          acc[u] += w.x * h.x;
          acc[u] += w.y * h.y;
          acc[u] += w.z * h.z;
          acc[u] += w.w * h.w;
        }
      }
      s = ((acc[0] + acc[1]) + (acc[2] + acc[3])) +
          ((acc[4] + acc[5]) + (acc[6] + acc[7]));
    }

    float* orow = out + (size_t)t * B_ * H_;
    float z = s + bh_j + orow[oidx];  // xproj_t read in place
    float hval = tanhf(z);
    orow[oidx] = hval;
    if (t == S_ - 1) out_last[oidx] = hval;

    if (t < S_ - 1) {
      // ---- group barrier: 64 blocks sharing this batch-group ----
      __threadfence();   // release: flush h stores (cross-XCD via L2 wb)
      __syncthreads();
      if (tid == 0) {
        atomicAdd(&bar[g], 1u);
        const unsigned tgt = 64u * (unsigned)(t + 1);
        while (__hip_atomic_load(&bar[g], __ATOMIC_RELAXED,
                                 __HIP_MEMORY_SCOPE_AGENT) < tgt)
          __builtin_amdgcn_s_sleep(1);
      }
      __syncthreads();
      __threadfence();   // acquire: invalidate so fresh h is read
    }
  }
}

// ---------------------------------------------------------------------------
// Launch. ws layout: WxT (256*1024 f32 = 1MB) | bar (4 x u32)
// ---------------------------------------------------------------------------
extern "C" void kernel_launch(void* const* d_in, const int* in_sizes, int n_in,
                              void* d_out, int out_size, void* d_ws, size_t ws_size,
                              hipStream_t stream) {
  const float* x  = (const float*)d_in[0];
  const float* Wx = (const float*)d_in[1];
  const float* bx = (const float*)d_in[2];
  const float* Wh = (const float*)d_in[3];
  const float* bh = (const float*)d_in[4];
  float* out = (float*)d_out;
  float* WxT = (float*)d_ws;                          // [I_][H_]
  unsigned* bar = (unsigned*)(WxT + (size_t)I_ * H_); // 4 counters

  hipMemsetAsync(bar, 0, 4 * sizeof(unsigned), stream);
  hipLaunchKernelGGL(transpose_k, dim3(I_ / 32, H_ / 32), dim3(256), 0, stream,
                     Wx, WxT, H_, I_);
  hipLaunchKernelGGL(xproj_kernel, dim3(H_ / 256, (S_ * B_) / 4), dim3(256), 0, stream,
                     x, WxT, bx, out);

  void* args[] = {(void*)&Wh, (void*)&bh, (void*)&out, (void*)&bar};
  hipLaunchCooperativeKernel((const void*)rnn_persistent, dim3(256), dim3(256),
                             args, 0, stream);
}

// Round 2
// 9582.437 us; speedup vs baseline: 2.7959x; 2.7959x over previous
//
#include <hip/hip_runtime.h>
#include <cstddef>

// Problem constants (from reference setup_inputs)
#define S_ 512
#define B_ 64
#define I_ 256
#define H_ 1024

// ---------------------------------------------------------------------------
// Transpose: out[c*R + r] = in[r*C + c].  R,C multiples of 32.
// Used only for Wx (xproj needs WxT). Wh is consumed row-major directly.
// ---------------------------------------------------------------------------
__global__ __launch_bounds__(256) void transpose_k(const float* __restrict__ in,
                                                   float* __restrict__ out,
                                                   int R, int C) {
  __shared__ float t[32][33];
  int c0 = blockIdx.x * 32, r0 = blockIdx.y * 32;
  int x = threadIdx.x & 31, y = threadIdx.x >> 5;
  for (int i = 0; i < 32; i += 8) {
    t[y + i][x] = in[(size_t)(r0 + y + i) * C + (c0 + x)];
  }
  __syncthreads();
  for (int i = 0; i < 32; i += 8) {
    out[(size_t)(c0 + y + i) * R + (r0 + x)] = t[x][y + i];
  }
}

// ---------------------------------------------------------------------------
// xproj: out[m*H + j] = dot(x[m, 0:256], WxT[:, j]) + bx[j]   (unchanged)
// ---------------------------------------------------------------------------
__global__ __launch_bounds__(256) void xproj_kernel(const float* __restrict__ x,
                                                    const float* __restrict__ WxT,
                                                    const float* __restrict__ bx,
                                                    float* __restrict__ out) {
  __shared__ float xs[4][I_];
  int tid = threadIdx.x;
  int j = blockIdx.x * 256 + tid;
  size_t m0 = (size_t)blockIdx.y * 4;
  const float* xrow = x + m0 * I_;
  for (int r = 0; r < 4; ++r) xs[r][tid] = xrow[(size_t)r * I_ + tid];
  __syncthreads();

  float bj = bx[j];
  float a0 = bj, a1 = bj, a2 = bj, a3 = bj;
  const float* wp = WxT + j;
  for (int k = 0; k < I_; k += 4) {
    float w0 = wp[(size_t)(k + 0) * H_];
    float w1 = wp[(size_t)(k + 1) * H_];
    float w2 = wp[(size_t)(k + 2) * H_];
    float w3 = wp[(size_t)(k + 3) * H_];
    float4 v0 = *(const float4*)&xs[0][k];
    float4 v1 = *(const float4*)&xs[1][k];
    float4 v2 = *(const float4*)&xs[2][k];
    float4 v3 = *(const float4*)&xs[3][k];
    a0 += w0 * v0.x + w1 * v0.y + w2 * v0.z + w3 * v0.w;
    a1 += w0 * v1.x + w1 * v1.y + w2 * v1.z + w3 * v1.w;
    a2 += w0 * v2.x + w1 * v2.y + w2 * v2.z + w3 * v2.w;
    a3 += w0 * v3.x + w1 * v3.y + w2 * v3.z + w3 * v3.w;
  }
  out[(m0 + 0) * H_ + j] = a0;
  out[(m0 + 1) * H_ + j] = a1;
  out[(m0 + 2) * H_ + j] = a2;
  out[(m0 + 3) * H_ + j] = a3;
}

// ---------------------------------------------------------------------------
// Persistent cooperative recurrence kernel, fence-free sync.
//   All cross-block data moves via agent-scope (sc1) accesses -> coherent at
//   L3, no buffer_wbl2/buffer_inv needed.  Barrier = vmcnt-drain + monotonic
//   L3 atomic counter per 16-batch group (64 blocks each, groups drift).
//   Wh tile (16 rows x 1024) lives in LDS for ALL 512 steps.
// ---------------------------------------------------------------------------
__global__ __launch_bounds__(256) void rnn_persistent(const float* __restrict__ Wh,
                                                      const float* __restrict__ bh,
                                                      float* __restrict__ out,
                                                      unsigned* __restrict__ bar) {
  __shared__ float4 Ws4[16][256];  // 64 KB, XOR-swizzled
  __shared__ float4 Hs4[16][256];  // 64 KB, XOR-swizzled

  const int tid = threadIdx.x;
  const int g  = blockIdx.x & 3;   // batch-group (16 batches)
  const int jt = blockIdx.x >> 2;  // j-tile
  const int j0 = jt * 16, b0 = g * 16;

  // ---- preload Wh rows j0..j0+15 into LDS once ----
  {
    const int rj = tid >> 4, kq = tid & 15;
    const float4* wh4 = (const float4*)(Wh + (size_t)(j0 + rj) * H_);
    #pragma unroll
    for (int it = 0; it < 16; ++it) {
      int k4 = kq + (it << 4);
      Ws4[rj][k4 ^ (rj & 7)] = wh4[k4];
    }
  }

  const int jj = tid & 15, bb = tid >> 4;
  const int jsw = jj & 7, bsw = bb & 7;
  const int sb = tid >> 4, sk = tid & 15;
  const float4* __restrict__ wrow = &Ws4[jj][0];
  const float4* __restrict__ hrow = &Hs4[bb][0];
  const float bh_j = bh[j0 + jj];
  const size_t oidx = (size_t)(b0 + bb) * H_ + (size_t)(j0 + jj);
  float* const out_last = out + (size_t)S_ * B_ * H_;

  __syncthreads();

  for (int t = 0; t < S_; ++t) {
    float* orow = out + (size_t)t * B_ * H_;
    float xv;
    float s = 0.f;

    if (t > 0) {
      // xproj read: independent normal load (line only ever touched by this
      // block + the pre-flushed xproj kernel -> fresh); overlaps staging.
      xv = orow[oidx];

      // ---- stage h_{t-1} rows b0..b0+15 via agent-scope 8B loads ----
      const unsigned long long* hsrc =
          (const unsigned long long*)(out + (size_t)(t - 1) * B_ * H_ +
                                      (size_t)b0 * H_);
      #pragma unroll
      for (int it = 0; it < 16; ++it) {
        int k4 = sk + (it << 4);
        unsigned long long d0 = __hip_atomic_load(
            &hsrc[(size_t)sb * 512 + (size_t)k4 * 2 + 0], __ATOMIC_RELAXED,
            __HIP_MEMORY_SCOPE_AGENT);
        unsigned long long d1 = __hip_atomic_load(
            &hsrc[(size_t)sb * 512 + (size_t)k4 * 2 + 1], __ATOMIC_RELAXED,
            __HIP_MEMORY_SCOPE_AGENT);
        float4 v;
        v.x = __uint_as_float((unsigned)d0);
        v.y = __uint_as_float((unsigned)(d0 >> 32));
        v.z = __uint_as_float((unsigned)d1);
        v.w = __uint_as_float((unsigned)(d1 >> 32));
        Hs4[sb][k4 ^ (sb & 7)] = v;
      }
      __syncthreads();

      // ---- dot: 256 float4 pairs from LDS, 8 interleaved accumulators ----
      float acc[8] = {0.f, 0.f, 0.f, 0.f, 0.f, 0.f, 0.f, 0.f};
      for (int kb = 0; kb < 256; kb += 8) {
        #pragma unroll
        for (int u = 0; u < 8; ++u) {
          float4 w = wrow[(kb + u) ^ jsw];
          float4 h = hrow[(kb + u) ^ bsw];
          acc[u] += w.x * h.x;
          acc[u] += w.y * h.y;
          acc[u] += w.z * h.z;
          acc[u] += w.w * h.w;
        }
      }
      s = ((acc[0] + acc[1]) + (acc[2] + acc[3])) +
          ((acc[4] + acc[5]) + (acc[6] + acc[7]));
    } else {
      xv = orow[oidx];
    }

    float z = s + bh_j + xv;
    float hval = tanhf(z);
    // agent-scope store: lands at L3, visible to all XCDs once vmcnt retires.
    __hip_atomic_store(&orow[oidx], hval, __ATOMIC_RELAXED,
                       __HIP_MEMORY_SCOPE_AGENT);
    if (t == S_ - 1) out_last[oidx] = hval;

    if (t < S_ - 1) {
      // each wave drains its own sc1 stores (ack'd at coherence point) ...
      asm volatile("s_waitcnt vmcnt(0)" ::: "memory");
      // ... all waves drained ...
      __syncthreads();
      // ... then one arrival per block on the monotonic group counter.
      if (tid == 0) {
        __hip_atomic_fetch_add(&bar[g], 1u, __ATOMIC_RELAXED,
                               __HIP_MEMORY_SCOPE_AGENT);
        const unsigned tgt = 64u * (unsigned)(t + 1);
        while (__hip_atomic_load(&bar[g], __ATOMIC_RELAXED,
                                 __HIP_MEMORY_SCOPE_AGENT) < tgt)
          __builtin_amdgcn_s_sleep(1);
      }
      __syncthreads();
    }
  }
}

// ---------------------------------------------------------------------------
// Launch. ws layout: WxT (256*1024 f32 = 1MB) | bar (4 x u32)
// ---------------------------------------------------------------------------
extern "C" void kernel_launch(void* const* d_in, const int* in_sizes, int n_in,
                              void* d_out, int out_size, void* d_ws, size_t ws_size,
                              hipStream_t stream) {
  const float* x  = (const float*)d_in[0];
  const float* Wx = (const float*)d_in[1];
  const float* bx = (const float*)d_in[2];
  const float* Wh = (const float*)d_in[3];
  const float* bh = (const float*)d_in[4];
  float* out = (float*)d_out;
  float* WxT = (float*)d_ws;                          // [I_][H_]
  unsigned* bar = (unsigned*)(WxT + (size_t)I_ * H_); // 4 counters

  hipMemsetAsync(bar, 0, 4 * sizeof(unsigned), stream);
  hipLaunchKernelGGL(transpose_k, dim3(I_ / 32, H_ / 32), dim3(256), 0, stream,
                     Wx, WxT, H_, I_);
  hipLaunchKernelGGL(xproj_kernel, dim3(H_ / 256, (S_ * B_) / 4), dim3(256), 0, stream,
                     x, WxT, bx, out);

  void* args[] = {(void*)&Wh, (void*)&bh, (void*)&out, (void*)&bar};
  hipLaunchCooperativeKernel((const void*)rnn_persistent, dim3(256), dim3(256),
                             args, 0, stream);
}

// Round 5
// 4494.497 us; speedup vs baseline: 5.9611x; 2.1320x over previous
//
#include <hip/hip_runtime.h>
#include <cstddef>

// Problem constants (from reference setup_inputs)
#define S_ 512
#define B_ 64
#define I_ 256
#define H_ 1024

#define NG 8   // batch groups (8 batches each)
#define GB 8   // batches per group
#define JT 32  // j rows per block
#define GBLK 32  // blocks per group (= 1024/JT)

// ---------------------------------------------------------------------------
// Transpose: out[c*R + r] = in[r*C + c].  R,C multiples of 32. (Wx only)
// ---------------------------------------------------------------------------
__global__ __launch_bounds__(256) void transpose_k(const float* __restrict__ in,
                                                   float* __restrict__ out,
                                                   int R, int C) {
  __shared__ float t[32][33];
  int c0 = blockIdx.x * 32, r0 = blockIdx.y * 32;
  int x = threadIdx.x & 31, y = threadIdx.x >> 5;
  for (int i = 0; i < 32; i += 8) {
    t[y + i][x] = in[(size_t)(r0 + y + i) * C + (c0 + x)];
  }
  __syncthreads();
  for (int i = 0; i < 32; i += 8) {
    out[(size_t)(c0 + y + i) * R + (r0 + x)] = t[x][y + i];
  }
}

// ---------------------------------------------------------------------------
// xproj: out[m*H + j] = dot(x[m, 0:256], WxT[:, j]) + bx[j]   (unchanged)
// ---------------------------------------------------------------------------
__global__ __launch_bounds__(256) void xproj_kernel(const float* __restrict__ x,
                                                    const float* __restrict__ WxT,
                                                    const float* __restrict__ bx,
                                                    float* __restrict__ out) {
  __shared__ float xs[4][I_];
  int tid = threadIdx.x;
  int j = blockIdx.x * 256 + tid;
  size_t m0 = (size_t)blockIdx.y * 4;
  const float* xrow = x + m0 * I_;
  for (int r = 0; r < 4; ++r) xs[r][tid] = xrow[(size_t)r * I_ + tid];
  __syncthreads();

  float bj = bx[j];
  float a0 = bj, a1 = bj, a2 = bj, a3 = bj;
  const float* wp = WxT + j;
  for (int k = 0; k < I_; k += 4) {
    float w0 = wp[(size_t)(k + 0) * H_];
    float w1 = wp[(size_t)(k + 1) * H_];
    float w2 = wp[(size_t)(k + 2) * H_];
    float w3 = wp[(size_t)(k + 3) * H_];
    float4 v0 = *(const float4*)&xs[0][k];
    float4 v1 = *(const float4*)&xs[1][k];
    float4 v2 = *(const float4*)&xs[2][k];
    float4 v3 = *(const float4*)&xs[3][k];
    a0 += w0 * v0.x + w1 * v0.y + w2 * v0.z + w3 * v0.w;
    a1 += w0 * v1.x + w1 * v1.y + w2 * v1.z + w3 * v1.w;
    a2 += w0 * v2.x + w1 * v2.y + w2 * v2.z + w3 * v2.w;
    a3 += w0 * v3.x + w1 * v3.y + w2 * v3.z + w3 * v3.w;
  }
  out[(m0 + 0) * H_ + j] = a0;
  out[(m0 + 1) * H_ + j] = a1;
  out[(m0 + 2) * H_ + j] = a2;
  out[(m0 + 3) * H_ + j] = a3;
}

// ---------------------------------------------------------------------------
// Persistent recurrence kernel, W-in-registers, grid = 256 (proven-launchable).
//   256 blocks = 32 j-tiles x 8 batch-groups; block tile = 32 j x 8 b.
//   thread (jj = tid>>3, ks = tid&7): holds Wh[j0+jj][ks*128 .. +128) in 32
//   float4 VGPRs forever.  Per step: stage h_prev rows (8 x 1024 f32 = 32KB)
//   into XOR-swizzled LDS (slot l -> l ^ ((l>>5)&7), read-hash == ks:
//   conflict-free); partial dot over the thread's 128-wide k-range for all 8
//   batches; 3-stage shfl_xor reduce over the 8 ks lanes; every thread owns
//   one (b, j) output.  Sync: monotonic L3 counter per group (32 blocks).
// ---------------------------------------------------------------------------
__global__ __launch_bounds__(256) void rnn_persistent(const float* __restrict__ Wh,
                                                      const float* __restrict__ bh,
                                                      float* __restrict__ out,
                                                      unsigned* __restrict__ bar) {
  __shared__ float4 Hs4[GB * 256];  // 32 KB; logical l stored at l ^ ((l>>5)&7)

  const int tid = threadIdx.x;
  const int g  = blockIdx.x & 7;   // batch-group
  const int jt = blockIdx.x >> 3;  // j-tile (0..31)
  const int j0 = jt * JT, b0 = g * GB;
  const int jj = tid >> 3;         // 0..31 : j row within tile
  const int ks = tid & 7;          // 0..7  : k-split (128 floats each)

  // ---- permanent W fragment: Wh[j0+jj][ks*128 .. +128) = 32 float4 ----
  float4 Wreg[32];
  {
    const float4* wp = (const float4*)(Wh + (size_t)(j0 + jj) * H_) + ks * 32;
    #pragma unroll
    for (int i = 0; i < 32; ++i) Wreg[i] = wp[i];
  }
  const float bh_j = bh[j0 + jj];
  // output ownership: lane ks = b owns (b0+b, j0+jj)
  const size_t oidx = (size_t)(b0 + ks) * H_ + (size_t)(j0 + jj);
  float* const out_last = out + (size_t)S_ * B_ * H_;
  unsigned* const barg = bar + (size_t)g * 32;  // 128B-padded counter

  for (int t = 0; t < S_; ++t) {
    float* orow = out + (size_t)t * B_ * H_;
    float xv = orow[oidx];  // xproj_t (written pre-kernel, line untouched since)

    float s = 0.f;
    if (t > 0) {
      // ---- stage h_{t-1}: 8 batched dwordx4 sc1 loads, one vmcnt drain ----
      const float* hsrc =
          (const float*)(out + (size_t)(t - 1) * B_ * H_ + (size_t)b0 * H_);
      float4 hv[8];
      #pragma unroll
      for (int q = 0; q < 8; ++q) {
        const float* ap = hsrc + (size_t)(q * 256 + tid) * 4;
        asm volatile("global_load_dwordx4 %0, %1, off sc1"
                     : "=v"(hv[q]) : "v"(ap));
      }
      // Drain the asm loads (and xv) before LDS writes consume hv.  LDS
      // writes are memory ops: the "memory" clobber orders them after this.
      asm volatile("s_waitcnt vmcnt(0)" ::: "memory");
      __builtin_amdgcn_sched_barrier(0);
      #pragma unroll
      for (int q = 0; q < 8; ++q) {
        int idx = q * 256 + tid;
        Hs4[idx ^ ((idx >> 5) & 7)] = hv[q];
      }
      __syncthreads();

      // ---- partial dot: k in [ks*128, +128), all 8 batches ----
      float acc[8] = {0.f, 0.f, 0.f, 0.f, 0.f, 0.f, 0.f, 0.f};
      const int kb = ks * 32;  // float4 base within a row
      #pragma unroll
      for (int i = 0; i < 32; ++i) {
        const float4 w = Wreg[i];
        const int l0 = (kb + i) ^ ks;  // swizzled offset (hash == ks here)
        #pragma unroll
        for (int b = 0; b < 8; ++b) {
          float4 h = Hs4[b * 256 + l0];
          acc[b] += w.x * h.x + w.y * h.y + w.z * h.z + w.w * h.w;
        }
      }
      // ---- reduce over the 8 ks lanes (lane bits 0..2), in-register ----
      #pragma unroll
      for (int b = 0; b < 8; ++b) {
        float v = acc[b];
        v += __shfl_xor(v, 1, 64);
        v += __shfl_xor(v, 2, 64);
        v += __shfl_xor(v, 4, 64);
        acc[b] = v;
      }
      // lane ks = b picks acc[b] (static-index select, no scratch)
      float sv = acc[0];
      #pragma unroll
      for (int b = 1; b < 8; ++b) sv = (ks == b) ? acc[b] : sv;
      s = sv;
    }

    float hval = tanhf(s + bh_j + xv);
    if (t == S_ - 1) out_last[oidx] = hval;
    __hip_atomic_store(&orow[oidx], hval, __ATOMIC_RELAXED,
                       __HIP_MEMORY_SCOPE_AGENT);

    if (t < S_ - 1) {
      asm volatile("s_waitcnt vmcnt(0)" ::: "memory");  // drain sc1 stores
      __syncthreads();  // all waves drained; also protects Hs4 reuse
      if (tid == 0) {
        __hip_atomic_fetch_add(barg, 1u, __ATOMIC_RELAXED,
                               __HIP_MEMORY_SCOPE_AGENT);
        const unsigned tgt = (unsigned)GBLK * (unsigned)(t + 1);
        while (__hip_atomic_load(barg, __ATOMIC_RELAXED,
                                 __HIP_MEMORY_SCOPE_AGENT) < tgt)
          __builtin_amdgcn_s_sleep(1);
      }
      __syncthreads();
    }
  }
}

// ---------------------------------------------------------------------------
// Launch. ws layout: WxT (256*1024 f32 = 1MB) | bar (8 x 32 u32, padded)
// ---------------------------------------------------------------------------
extern "C" void kernel_launch(void* const* d_in, const int* in_sizes, int n_in,
                              void* d_out, int out_size, void* d_ws, size_t ws_size,
                              hipStream_t stream) {
  const float* x  = (const float*)d_in[0];
  const float* Wx = (const float*)d_in[1];
  const float* bx = (const float*)d_in[2];
  const float* Wh = (const float*)d_in[3];
  const float* bh = (const float*)d_in[4];
  float* out = (float*)d_out;
  float* WxT = (float*)d_ws;                          // [I_][H_]
  unsigned* bar = (unsigned*)(WxT + (size_t)I_ * H_); // 8 padded counters

  (void)hipMemsetAsync(bar, 0, NG * 32 * sizeof(unsigned), stream);
  hipLaunchKernelGGL(transpose_k, dim3(I_ / 32, H_ / 32), dim3(256), 0, stream,
                     Wx, WxT, H_, I_);
  hipLaunchKernelGGL(xproj_kernel, dim3(H_ / 256, (S_ * B_) / 4), dim3(256), 0, stream,
                     x, WxT, bx, out);

  void* args[] = {(void*)&Wh, (void*)&bh, (void*)&out, (void*)&bar};
  (void)hipLaunchCooperativeKernel((const void*)rnn_persistent, dim3(256),
                                   dim3(256), args, 0, stream);
}

// Round 8
// 4294.762 us; speedup vs baseline: 6.2383x; 1.0465x over previous
//
#include <hip/hip_runtime.h>
#include <cstddef>

// Problem constants (from reference setup_inputs)
#define S_ 512
#define B_ 64
#define I_ 256
#define H_ 1024

#define NG 8     // batch groups (8 batches each)
#define GB 8     // batches per group
#define JT 32    // j rows per block
#define GBLK 32  // blocks per group (= 1024/JT)

// ---------------------------------------------------------------------------
// Transpose: out[c*R + r] = in[r*C + c].  R,C multiples of 32. (Wx only)
// ---------------------------------------------------------------------------
__global__ __launch_bounds__(256) void transpose_k(const float* __restrict__ in,
                                                   float* __restrict__ out,
                                                   int R, int C) {
  __shared__ float t[32][33];
  int c0 = blockIdx.x * 32, r0 = blockIdx.y * 32;
  int x = threadIdx.x & 31, y = threadIdx.x >> 5;
  for (int i = 0; i < 32; i += 8) {
    t[y + i][x] = in[(size_t)(r0 + y + i) * C + (c0 + x)];
  }
  __syncthreads();
  for (int i = 0; i < 32; i += 8) {
    out[(size_t)(c0 + y + i) * R + (r0 + x)] = t[x][y + i];
  }
}

// ---------------------------------------------------------------------------
// xproj: out[m*H + j] = dot(x[m, 0:256], WxT[:, j]) + bx[j]
// 8 m-rows per block.  grid = (H/256 = 4, S*B/8 = 4096)
// ---------------------------------------------------------------------------
__global__ __launch_bounds__(256) void xproj_kernel(const float* __restrict__ x,
                                                    const float* __restrict__ WxT,
                                                    const float* __restrict__ bx,
                                                    float* __restrict__ out) {
  __shared__ float xs[8][I_];
  int tid = threadIdx.x;
  int j = blockIdx.x * 256 + tid;
  size_t m0 = (size_t)blockIdx.y * 8;
  const float* xrow = x + m0 * I_;
  #pragma unroll
  for (int r = 0; r < 8; ++r) xs[r][tid] = xrow[(size_t)r * I_ + tid];
  __syncthreads();

  float bj = bx[j];
  float a[8];
  #pragma unroll
  for (int r = 0; r < 8; ++r) a[r] = bj;
  const float* wp = WxT + j;
  for (int k = 0; k < I_; k += 4) {
    float w0 = wp[(size_t)(k + 0) * H_];
    float w1 = wp[(size_t)(k + 1) * H_];
    float w2 = wp[(size_t)(k + 2) * H_];
    float w3 = wp[(size_t)(k + 3) * H_];
    #pragma unroll
    for (int r = 0; r < 8; ++r) {
      float4 v = *(const float4*)&xs[r][k];
      a[r] += w0 * v.x + w1 * v.y + w2 * v.z + w3 * v.w;
    }
  }
  #pragma unroll
  for (int r = 0; r < 8; ++r) out[(m0 + r) * H_ + j] = a[r];
}

// ---------------------------------------------------------------------------
// Persistent recurrence kernel, W-in-registers, grid = 256 x 512 threads.
//   256 blocks = 32 j-tiles x 8 batch-groups; block tile = 32 j x 8 b.
//   8 waves/block -> 2 waves/SIMD: stage/LDS/barrier latency hides under the
//   other wave's FMA stream.
//   thread (jj = tid>>4, ks = tid&15): holds Wh[j0+jj][ks*64 .. +64) in 16
//   float4 VGPRs forever.  Per step: stage h_prev (8 x 1024 f32 = 32KB) into
//   XOR-swizzled LDS (float4 slot f stored at f ^ ((f>>4)&7)).
//   Read pairing (the round-7 bug): logical col kb+i lives at PHYSICAL
//   kb + (i^ksw), and must pair with Wreg[i] — XOR exactly once.
//   Partial dot over the thread's 64-wide k-range for all 8 batches; 4-stage
//   shfl_xor reduce over the 16 ks lanes; lane ks<8 owns output (b0+ks, j).
//   Sync: per-group flag array (32 flags), plain sc1 stores + parallel poll.
// ---------------------------------------------------------------------------
__global__ __launch_bounds__(512) void rnn_persistent(const float* __restrict__ Wh,
                                                      const float* __restrict__ bh,
                                                      float* __restrict__ out,
                                                      unsigned* __restrict__ flags) {
  __shared__ float4 Hs4[GB * 256];  // 32 KB; float4 slot f at f ^ ((f>>4)&7)

  const int tid = threadIdx.x;
  const int g  = blockIdx.x & 7;   // batch-group
  const int jt = blockIdx.x >> 3;  // j-tile (0..31)
  const int j0 = jt * JT, b0 = g * GB;
  const int jj = tid >> 4;         // 0..31 : j row within tile
  const int ks = tid & 15;         // 0..15 : k-split (64 floats each)
  const int ksw = ks & 7;

  // ---- permanent W fragment: Wh[j0+jj][ks*64 .. +64) = 16 float4 ----
  float4 Wreg[16];
  {
    const float4* wp = (const float4*)(Wh + (size_t)(j0 + jj) * H_) + ks * 16;
    #pragma unroll
    for (int i = 0; i < 16; ++i) Wreg[i] = wp[i];
  }
  const float bh_j = bh[j0 + jj];
  // lane ks = b (b < 8) owns output (b0+b, j0+jj); ks>=8 reads a dup row.
  const size_t oidx = (size_t)(b0 + ksw) * H_ + (size_t)(j0 + jj);
  float* const out_last = out + (size_t)S_ * B_ * H_;
  unsigned* const flagg = flags + (size_t)g * GBLK;

  for (int t = 0; t < S_; ++t) {
    float* orow = out + (size_t)t * B_ * H_;
    float xv = orow[oidx];  // xproj_t (written pre-kernel, line untouched since)

    float s = 0.f;
    if (t > 0) {
      // ---- stage h_{t-1}: 4 batched dwordx4 sc1 loads, one vmcnt drain ----
      const float* hsrc =
          (const float*)(out + (size_t)(t - 1) * B_ * H_ + (size_t)b0 * H_);
      float4 hv[4];
      #pragma unroll
      for (int q = 0; q < 4; ++q) {
        const float* ap = hsrc + (size_t)(q * 512 + tid) * 4;
        asm volatile("global_load_dwordx4 %0, %1, off sc1"
                     : "=v"(hv[q]) : "v"(ap));
      }
      asm volatile("s_waitcnt vmcnt(0)" ::: "memory");
      __builtin_amdgcn_sched_barrier(0);
      #pragma unroll
      for (int q = 0; q < 4; ++q) {
        int f = q * 512 + tid;
        Hs4[f ^ ((f >> 4) & 7)] = hv[q];
      }
      __syncthreads();

      // ---- partial dot: k in [ks*64, +64), all 8 batches ----
      float acc[8] = {0.f, 0.f, 0.f, 0.f, 0.f, 0.f, 0.f, 0.f};
      const int kb = ks * 16;  // float4 base within a row
      #pragma unroll
      for (int i = 0; i < 16; ++i) {
        const int l0 = kb + (i ^ ksw);  // PHYSICAL slot of logical col kb+i
        const float4 w = Wreg[i];       // W for logical col kb+i (XOR once!)
        #pragma unroll
        for (int b = 0; b < 8; ++b) {
          float4 h = Hs4[b * 256 + l0];
          acc[b] += w.x * h.x + w.y * h.y + w.z * h.z + w.w * h.w;
        }
      }
      // ---- reduce over the 16 ks lanes (lane bits 0..3), in-register ----
      #pragma unroll
      for (int b = 0; b < 8; ++b) {
        float v = acc[b];
        v += __shfl_xor(v, 1, 64);
        v += __shfl_xor(v, 2, 64);
        v += __shfl_xor(v, 4, 64);
        v += __shfl_xor(v, 8, 64);
        acc[b] = v;
      }
      // lane ks = b picks acc[b] (static-index select, no scratch)
      float sv = acc[0];
      #pragma unroll
      for (int b = 1; b < 8; ++b) sv = (ks == b) ? acc[b] : sv;
      s = sv;
    }

    if (ks < GB) {
      float hval = tanhf(s + bh_j + xv);
      if (t == S_ - 1) out_last[oidx] = hval;
      __hip_atomic_store(&orow[oidx], hval, __ATOMIC_RELAXED,
                         __HIP_MEMORY_SCOPE_AGENT);
    }

    if (t < S_ - 1) {
      asm volatile("s_waitcnt vmcnt(0)" ::: "memory");  // drain sc1 h stores
      __syncthreads();  // all waves drained; Hs4 safe to overwrite next step
      if (tid == 0) {
        __hip_atomic_store(&flagg[jt], (unsigned)(t + 1), __ATOMIC_RELAXED,
                           __HIP_MEMORY_SCOPE_AGENT);
      }
      if (tid < 64) {
        unsigned* fp = &flagg[tid & 31];
        const unsigned tgt = (unsigned)(t + 1);
        while (__hip_atomic_load(fp, __ATOMIC_RELAXED,
                                 __HIP_MEMORY_SCOPE_AGENT) < tgt)
          __builtin_amdgcn_s_sleep(1);
      }
      __syncthreads();
    }
  }
}

// ---------------------------------------------------------------------------
// Launch. ws layout: WxT (256*1024 f32 = 1MB) | flags (8 x 32 u32)
// If the cooperative launch is refused (validation quirk), fall back to a
// plain launch of the same shape: 256 blocks on 256 CUs are all-resident.
// ---------------------------------------------------------------------------
extern "C" void kernel_launch(void* const* d_in, const int* in_sizes, int n_in,
                              void* d_out, int out_size, void* d_ws, size_t ws_size,
                              hipStream_t stream) {
  const float* x  = (const float*)d_in[0];
  const float* Wx = (const float*)d_in[1];
  const float* bx = (const float*)d_in[2];
  const float* Wh = (const float*)d_in[3];
  const float* bh = (const float*)d_in[4];
  float* out = (float*)d_out;
  float* WxT = (float*)d_ws;                            // [I_][H_]
  unsigned* flags = (unsigned*)(WxT + (size_t)I_ * H_); // 8 x 32

  (void)hipMemsetAsync(flags, 0, NG * GBLK * sizeof(unsigned), stream);
  hipLaunchKernelGGL(transpose_k, dim3(I_ / 32, H_ / 32), dim3(256), 0, stream,
                     Wx, WxT, H_, I_);
  hipLaunchKernelGGL(xproj_kernel, dim3(H_ / 256, (S_ * B_) / 8), dim3(256), 0, stream,
                     x, WxT, bx, out);

  void* args[] = {(void*)&Wh, (void*)&bh, (void*)&out, (void*)&flags};
  hipError_t e = hipLaunchCooperativeKernel((const void*)rnn_persistent,
                                            dim3(256), dim3(512), args, 0, stream);
  if (e != hipSuccess) {
    hipLaunchKernelGGL(rnn_persistent, dim3(256), dim3(512), 0, stream,
                       Wh, bh, out, flags);
  }
}